// Round 9
// baseline (198.079 us; speedup 1.0000x reference)
//
#include <hip/hip_runtime.h>
#include <hip/hip_fp16.h>

// SuppLayer: out[b,c] = exp( sum_s x[b, cm[c,s]] * w[c,s] )
// B=4096, NCLASS=1000, NSUPP=64, NCHUNK=4096.
//
// R18: R16's ordered overlap schedule, resized to the 64-VGPR envelope
// by R17's packed-fp16 math.
//  Session laws: (1) 1024-thr blocks get exactly 64 VGPRs on gfx950 —
//  exceed it and scratch traffic eats the win (R13-R16). (2) vmcnt is a
//  single in-order counter — a wait on load L drains ALL older loads, so
//  streamed x loads survive only if every wait during their flight
//  targets loads issued BEFORE them (R16's construction, correct but too
//  fat at depth-4). (3) pk_fma_f16 gather with flush@4sg passes absmax
//  with 3x headroom (R17: 5.4e8 vs 1.62e9).
//  Design: BT=16, 1 block/CU. Stage lo (8 rows) -> bar -> 16 gather
//  passes over tlo with a depth-2 cm/w rotation (16 regs); hi rows
//  stream as 4 one-column chunks (8 regs) issued at pass 0/4/8/12
//  AFTER that pass's refill (SB-pinned), cvt'd 4 passes later. First
//  drain of chunk@i is gather@i+3's wait on refill@i+1 -> 3-pass flight
//  (~1.8us) >= 1.33us/chunk stream need. Live set ~56 < 64.
//  Hi phase gathers thi with the same rotation, no streaming.
//  Slot = 16 B = 8 rows fp16; read quad = idx&7; pre-pass counting-sorts
//  by (idx-c)&7 (balanced quads across a wave) and stores weights as
//  broadcast half2.

constexpr int B_       = 4096;
constexpr int NCLASS_  = 1000;
constexpr int NSUPP_   = 64;
constexpr int NCHUNK_  = 4096;
constexpr int BT       = 16;     // batch rows per block
constexpr int THREADS_ = 1024;
constexpr int SG_      = NSUPP_ / 4;            // 16 int4 groups
constexpr size_t CMT_BYTES = (size_t)SG_ * NCLASS_ * 16;   // 256 KB
constexpr size_t WS_NEEDED = 2 * CMT_BYTES;                // 512 KB

// ---- pre-pass: one wave per class. Sort 64 (idx,w) by key=(idx-c)&7 and
// write to [sg][class] transposed layout; weights as BROADCAST half2. ----
__global__ __launch_bounds__(256)
void build_cw_kernel(const int*   __restrict__ cm,
                     const float* __restrict__ w,
                     int*         __restrict__ cmT,
                     __half2*     __restrict__ wTh)
{
    const int t    = threadIdx.x;
    const int c    = blockIdx.x * 4 + (t >> 6);   // 4 classes per block
    const int lane = t & 63;
    if (c >= NCLASS_) return;                      // grid=250 -> never taken

    const int   idx = cm[c * NSUPP_ + lane];
    const float wv  = w [c * NSUPP_ + lane];
    const int   key = (idx - c) & 7;               // read quad = idx&7

    const unsigned long long below = ((unsigned long long)1 << lane) - 1ull;
    int j = 0;
    #pragma unroll
    for (int r = 0; r < 8; ++r) {
        const unsigned long long m = __ballot(key == r);
        if (key > r)  j += __popcll(m);
        if (key == r) j += __popcll(m & below);
    }

    const int dst = ((j >> 2) * NCLASS_ + c) * 4 + (j & 3);
    cmT[dst] = idx;
    wTh[dst] = __float2half2_rn(wv);
}

// float bits <-> packed half2, no address-of-local
static __device__ __forceinline__ __half2 f2h2(const float u) {
    union U { float f; __half2 h; } uu;
    uu.f = u;
    return uu.h;
}
static __device__ __forceinline__ float h2f(const __half2 h) {
    union U { __half2 h; float f; } uu;
    uu.h = h;
    return uu.f;
}

#define SB() __builtin_amdgcn_sched_barrier(0)

// one support: slot float4 d (8 rows fp16), broadcast half2 weight wj
#define GSUPP(d, wj)                               \
    a0 = __hfma2(f2h2((d).x), (wj), a0);           \
    a1 = __hfma2(f2h2((d).y), (wj), a1);           \
    a2 = __hfma2(f2h2((d).z), (wj), a2);           \
    a3 = __hfma2(f2h2((d).w), (wj), a3);

// gather one sg group from slot J (2 ds_read_b128 at a time: 8 d-temps)
#define GATHER(J, T4) {                            \
    {   const float4 d0_ = (T4)[cwS##J.x];         \
        const float4 d1_ = (T4)[cwS##J.y];         \
        const __half2 w0_ = f2h2(whS##J.x);        \
        const __half2 w1_ = f2h2(whS##J.y);        \
        GSUPP(d0_, w0_)                            \
        GSUPP(d1_, w1_) }                          \
    {   const float4 d2_ = (T4)[cwS##J.z];         \
        const float4 d3_ = (T4)[cwS##J.w];         \
        const __half2 w2_ = f2h2(whS##J.z);        \
        const __half2 w3_ = f2h2(whS##J.w);        \
        GSUPP(d2_, w2_)                            \
        GSUPP(d3_, w3_) } }

// refill slot J with sg group S (2 VMEM loads; !USET converts to half2)
#define REFILL(J, S)                                                         \
    if constexpr (USET) {                                                    \
        cwS##J = cmT [(S) * NCLASS_ + c];                                    \
        whS##J = wTh4[(S) * NCLASS_ + c];                                    \
    } else {                                                                 \
        cwS##J = reinterpret_cast<const int4*>(cmap + c * NSUPP_)[(S)];      \
        const float4 wf_ =                                                   \
            reinterpret_cast<const float4*>(wSupp + c * NSUPP_)[(S)];        \
        float4 wp_;                                                          \
        wp_.x = h2f(__float2half2_rn(wf_.x));                                \
        wp_.y = h2f(__float2half2_rn(wf_.y));                                \
        wp_.z = h2f(__float2half2_rn(wf_.z));                                \
        wp_.w = h2f(__float2half2_rn(wf_.w));                                \
        whS##J = wp_;                                                        \
    }

#define FLUSH_ACC() {                              \
    float2 t_;                                     \
    t_ = __half22float2(a0); f0x += t_.x; f0y += t_.y; \
    t_ = __half22float2(a1); f1x += t_.x; f1y += t_.y; \
    t_ = __half22float2(a2); f2x += t_.x; f2y += t_.y; \
    t_ = __half22float2(a3); f3x += t_.x; f3y += t_.y; \
    a0 = z_; a1 = z_; a2 = z_; a3 = z_; }

// issue one hi-row column chunk (8 loads) into hv0..7
#define CHUNK_ISSUE(Q) {                                                     \
    const size_t colq_ = (size_t)t + THREADS_ * (Q);                         \
    hv0 = x[(size_t)(rb +  8) * NCHUNK_ + colq_];                            \
    hv1 = x[(size_t)(rb +  9) * NCHUNK_ + colq_];                            \
    hv2 = x[(size_t)(rb + 10) * NCHUNK_ + colq_];                            \
    hv3 = x[(size_t)(rb + 11) * NCHUNK_ + colq_];                            \
    hv4 = x[(size_t)(rb + 12) * NCHUNK_ + colq_];                            \
    hv5 = x[(size_t)(rb + 13) * NCHUNK_ + colq_];                            \
    hv6 = x[(size_t)(rb + 14) * NCHUNK_ + colq_];                            \
    hv7 = x[(size_t)(rb + 15) * NCHUNK_ + colq_]; }

// convert chunk Q and write its thi slot (one b128)
#define CHUNK_CVT(Q) {                                                       \
    const size_t colq_ = (size_t)t + THREADS_ * (Q);                         \
    float4 pk_;                                                              \
    pk_.x = h2f(__floats2half2_rn(hv0, hv1));                                \
    pk_.y = h2f(__floats2half2_rn(hv2, hv3));                                \
    pk_.z = h2f(__floats2half2_rn(hv4, hv5));                                \
    pk_.w = h2f(__floats2half2_rn(hv6, hv7));                                \
    *reinterpret_cast<float4*>(&thi[colq_ * 4]) = pk_; }

template <bool USET>
__global__ __launch_bounds__(THREADS_)
void supp_gather_kernel(const float* __restrict__ x,
                        const float* __restrict__ wSupp,
                        const int*   __restrict__ cmap,
                        const float4* __restrict__ wTh4,
                        const int4*   __restrict__ cmT,
                        float*       __restrict__ out)
{
    // two 64 KB halves; slot idx = 16 B = 8 rows as half2 pairs
    __shared__ __align__(16) __half2 tile[NCHUNK_ * 8];
    __half2* tlo = tile;
    __half2* thi = tile + NCHUNK_ * 4;
    const float4* tlo4 = reinterpret_cast<const float4*>(tlo);
    const float4* thi4 = reinterpret_cast<const float4*>(thi);

    const int t  = threadIdx.x;
    const int rb = blockIdx.x * BT;   // first batch row of this tile
    const int c  = (t < NCLASS_) ? t : NCLASS_ - 1;   // clamp tail

    // ---- depth-2 rotating cm/w slots (16 VGPR) ----
    int4   cwS0, cwS1;
    float4 whS0, whS1;
    REFILL(0, 0) REFILL(1, 1)

    // ---- stage rows rb..rb+7 -> fp16 -> tlo ----
    #pragma unroll
    for (int p = 0; p < NCHUNK_ / THREADS_; ++p) {
        const size_t col = (size_t)t + THREADS_ * p;
        float v0 = x[(size_t)(rb + 0) * NCHUNK_ + col];
        float v1 = x[(size_t)(rb + 1) * NCHUNK_ + col];
        float v2 = x[(size_t)(rb + 2) * NCHUNK_ + col];
        float v3 = x[(size_t)(rb + 3) * NCHUNK_ + col];
        float v4 = x[(size_t)(rb + 4) * NCHUNK_ + col];
        float v5 = x[(size_t)(rb + 5) * NCHUNK_ + col];
        float v6 = x[(size_t)(rb + 6) * NCHUNK_ + col];
        float v7 = x[(size_t)(rb + 7) * NCHUNK_ + col];
        float4 pk;
        pk.x = h2f(__floats2half2_rn(v0, v1));
        pk.y = h2f(__floats2half2_rn(v2, v3));
        pk.z = h2f(__floats2half2_rn(v4, v5));
        pk.w = h2f(__floats2half2_rn(v6, v7));
        *reinterpret_cast<float4*>(&tlo[col * 4]) = pk;
    }
    __syncthreads();

    const __half2 z_ = __floats2half2_rn(0.f, 0.f);
    __half2 a0 = z_, a1 = z_, a2 = z_, a3 = z_;
    float f0x = 0.f, f0y = 0.f, f1x = 0.f, f1y = 0.f;
    float f2x = 0.f, f2y = 0.f, f3x = 0.f, f3y = 0.f;
    float hv0, hv1, hv2, hv3, hv4, hv5, hv6, hv7;

    // ---- lo gather (16 passes) || hi stream (4 chunks) ----
    // pass i: GATHER(slot i&1)=sg_i, REFILL(slot, sg i+2); chunks at
    // 4-boundaries issued AFTER the refill (SB-pinned) so chunk@i's
    // first drain is gather@i+3's wait on refill@i+1 (3-pass flight).
    /* 0*/ GATHER(0, tlo4) REFILL(0,  2) SB(); CHUNK_ISSUE(0) SB();
    /* 1*/ GATHER(1, tlo4) REFILL(1,  3) SB();
    /* 2*/ GATHER(0, tlo4) REFILL(0,  4) SB();
    /* 3*/ GATHER(1, tlo4) REFILL(1,  5) FLUSH_ACC() SB();
    /* 4*/ CHUNK_CVT(0) SB();
           GATHER(0, tlo4) REFILL(0,  6) SB(); CHUNK_ISSUE(1) SB();
    /* 5*/ GATHER(1, tlo4) REFILL(1,  7) SB();
    /* 6*/ GATHER(0, tlo4) REFILL(0,  8) SB();
    /* 7*/ GATHER(1, tlo4) REFILL(1,  9) FLUSH_ACC() SB();
    /* 8*/ CHUNK_CVT(1) SB();
           GATHER(0, tlo4) REFILL(0, 10) SB(); CHUNK_ISSUE(2) SB();
    /* 9*/ GATHER(1, tlo4) REFILL(1, 11) SB();
    /*10*/ GATHER(0, tlo4) REFILL(0, 12) SB();
    /*11*/ GATHER(1, tlo4) REFILL(1, 13) FLUSH_ACC() SB();
    /*12*/ CHUNK_CVT(2) SB();
           GATHER(0, tlo4) REFILL(0, 14) SB(); CHUNK_ISSUE(3) SB();
    /*13*/ GATHER(1, tlo4) REFILL(1, 15) SB();
    /*14*/ GATHER(0, tlo4) SB();
    /*15*/ GATHER(1, tlo4) FLUSH_ACC() SB();
    CHUNK_CVT(3) SB();

    // ---- lo rows complete: exp + store (drained at the barrier) ----
    if (t < NCLASS_) {
        out[(size_t)(rb + 0) * NCLASS_ + c] = __expf(f0x);
        out[(size_t)(rb + 1) * NCLASS_ + c] = __expf(f0y);
        out[(size_t)(rb + 2) * NCLASS_ + c] = __expf(f1x);
        out[(size_t)(rb + 3) * NCLASS_ + c] = __expf(f1y);
        out[(size_t)(rb + 4) * NCLASS_ + c] = __expf(f2x);
        out[(size_t)(rb + 5) * NCLASS_ + c] = __expf(f2y);
        out[(size_t)(rb + 6) * NCLASS_ + c] = __expf(f3x);
        out[(size_t)(rb + 7) * NCLASS_ + c] = __expf(f3y);
    }
    // re-prime slots for the hi phase (drained harmlessly at the barrier)
    REFILL(0, 0) REFILL(1, 1)
    __syncthreads();

    // ---- hi gather: 16 passes over thi, same rotation, no streaming ----
    a0 = z_; a1 = z_; a2 = z_; a3 = z_;
    f0x = 0.f; f0y = 0.f; f1x = 0.f; f1y = 0.f;
    f2x = 0.f; f2y = 0.f; f3x = 0.f; f3y = 0.f;
    GATHER(0, thi4) REFILL(0,  2)
    GATHER(1, thi4) REFILL(1,  3)
    GATHER(0, thi4) REFILL(0,  4)
    GATHER(1, thi4) REFILL(1,  5) FLUSH_ACC()
    GATHER(0, thi4) REFILL(0,  6)
    GATHER(1, thi4) REFILL(1,  7)
    GATHER(0, thi4) REFILL(0,  8)
    GATHER(1, thi4) REFILL(1,  9) FLUSH_ACC()
    GATHER(0, thi4) REFILL(0, 10)
    GATHER(1, thi4) REFILL(1, 11)
    GATHER(0, thi4) REFILL(0, 12)
    GATHER(1, thi4) REFILL(1, 13) FLUSH_ACC()
    GATHER(0, thi4) REFILL(0, 14)
    GATHER(1, thi4) REFILL(1, 15)
    GATHER(0, thi4)
    GATHER(1, thi4) FLUSH_ACC()

    if (t < NCLASS_) {
        out[(size_t)(rb +  8) * NCLASS_ + c] = __expf(f0x);
        out[(size_t)(rb +  9) * NCLASS_ + c] = __expf(f0y);
        out[(size_t)(rb + 10) * NCLASS_ + c] = __expf(f1x);
        out[(size_t)(rb + 11) * NCLASS_ + c] = __expf(f1y);
        out[(size_t)(rb + 12) * NCLASS_ + c] = __expf(f2x);
        out[(size_t)(rb + 13) * NCLASS_ + c] = __expf(f2y);
        out[(size_t)(rb + 14) * NCLASS_ + c] = __expf(f3x);
        out[(size_t)(rb + 15) * NCLASS_ + c] = __expf(f3y);
    }
}

extern "C" void kernel_launch(void* const* d_in, const int* in_sizes, int n_in,
                              void* d_out, int out_size, void* d_ws, size_t ws_size,
                              hipStream_t stream) {
    const float* x  = (const float*)d_in[0];   // (B, NCHUNK) fp32
    const float* w  = (const float*)d_in[1];   // (NCLASS, NSUPP) fp32
    const int*   cm = (const int*)d_in[2];     // (NCLASS, NSUPP) int32
    float*       o  = (float*)d_out;           // (B, NCLASS) fp32

    int*     cmT = (int*)d_ws;
    __half2* wTh = (__half2*)((char*)d_ws + CMT_BYTES);

    const dim3 grid(B_ / BT);                  // 256 blocks, 1 per CU
    if (ws_size >= WS_NEEDED) {
        build_cw_kernel<<<dim3((NCLASS_ + 3) / 4), dim3(256), 0, stream>>>(
            cm, w, cmT, wTh);
        supp_gather_kernel<true><<<grid, dim3(THREADS_), 0, stream>>>(
            x, w, cm, (const float4*)wTh, (const int4*)cmT, o);
    } else {
        supp_gather_kernel<false><<<grid, dim3(THREADS_), 0, stream>>>(
            x, w, cm, (const float4*)wTh, (const int4*)cmT, o);
    }
}

// Round 10
// 114.161 us; speedup vs baseline: 1.7351x; 1.7351x over previous
//
#include <hip/hip_runtime.h>
#include <hip/hip_fp16.h>

// SuppLayer: out[b,c] = exp( sum_s x[b, cm[c,s]] * w[c,s] )
// B=4096, NCLASS=1000, NSUPP=64, NCHUNK=4096.
//
// R19: R17 (session best, 110.9us) + greedy conflict-free cm placement.
//  Session laws: (1) 1024-thr blocks get exactly 64 VGPRs; exceeding
//  spills at ruinous cost. (2) sched_barrier-pinned overlap schedules
//  spill EVEN when the naive live-set fits (R16/R18): the walls forbid
//  remat across sections. So: no SB, no overlap — R17's SB-free body.
//  (3) pk_fma_f16 + flush@4sg passes absmax with 3x headroom.
//  New (pre-pass only): a ds_read at sorted position j uses bank-quad
//  (key_j(c)+c)&7, conflict-free across lanes iff key_j is the SAME for
//  all classes. Sort-by-key leaves ~30/64 positions in histogram-boundary
//  jitter zones (measured 3.15M conflict cycles, ~75% overhead).
//  Greedy placement targets key == j&7: pair with within-key rank rk<8
//  -> j = rk*8+key; leftovers (E~8.5/64) fill under-full keys' holes by
//  matched ordinals (bijective). ~13% misplaced vs ~47% -> ~3x fewer
//  conflicts. Gather kernel is byte-identical to R17.
//  Structure: BT=8 rows, 512 blocks (2/CU), 64 KB tile, slot = 16 B =
//  8 rows fp16, read quad = idx&7, one-deep cm/w prefetch, weights as
//  broadcast half2, v_pk_fma_f16 inner loop, f32 flush every 4 sg.

constexpr int B_       = 4096;
constexpr int NCLASS_  = 1000;
constexpr int NSUPP_   = 64;
constexpr int NCHUNK_  = 4096;
constexpr int BT       = 8;      // batch rows per block
constexpr int THREADS_ = 1024;
constexpr int SG_      = NSUPP_ / 4;            // 16 int4 groups
constexpr size_t CMT_BYTES = (size_t)SG_ * NCLASS_ * 16;   // 256 KB
constexpr size_t WS_NEEDED = 2 * CMT_BYTES;                // 512 KB

// ---- pre-pass: one wave per class. Place 64 (idx,w) pairs so position j
// holds a pair with key (idx-c)&7 == j&7 wherever possible (greedy with
// ordinal-matched overflow), then write [sg][class] transposed layout.
// Weights stored as BROADCAST half2. All-register rank computation. ----
__global__ __launch_bounds__(256)
void build_cw_kernel(const int*   __restrict__ cm,
                     const float* __restrict__ w,
                     int*         __restrict__ cmT,
                     __half2*     __restrict__ wTh)
{
    const int t    = threadIdx.x;
    const int c    = blockIdx.x * 4 + (t >> 6);   // 4 classes per block
    const int lane = t & 63;
    if (c >= NCLASS_) return;                      // grid=250 -> never taken

    const int   idx = cm[c * NSUPP_ + lane];
    const float wv  = w [c * NSUPP_ + lane];
    const int   key = (idx - c) & 7;               // read quad = idx&7

    // per-key population n[r] and my within-key stable rank
    const unsigned long long below = ((unsigned long long)1 << lane) - 1ull;
    int n0, n1, n2, n3, n4, n5, n6, n7;
    int myrk = 0;
    {
        unsigned long long m;
        m = __ballot(key == 0); n0 = __popcll(m); if (key == 0) myrk = __popcll(m & below);
        m = __ballot(key == 1); n1 = __popcll(m); if (key == 1) myrk = __popcll(m & below);
        m = __ballot(key == 2); n2 = __popcll(m); if (key == 2) myrk = __popcll(m & below);
        m = __ballot(key == 3); n3 = __popcll(m); if (key == 3) myrk = __popcll(m & below);
        m = __ballot(key == 4); n4 = __popcll(m); if (key == 4) myrk = __popcll(m & below);
        m = __ballot(key == 5); n5 = __popcll(m); if (key == 5) myrk = __popcll(m & below);
        m = __ballot(key == 6); n6 = __popcll(m); if (key == 6) myrk = __popcll(m & below);
        m = __ballot(key == 7); n7 = __popcll(m); if (key == 7) myrk = __popcll(m & below);
    }

    int j;
    if (myrk < 8) {
        // direct slot: position j has j&7 == key  -> quad rotates with lane
        j = myrk * 8 + key;
    } else {
        // leftover ordinal o = excess pairs lexicographically before me
        int o = myrk - 8;
        if (key > 0) o += max(n0 - 8, 0);
        if (key > 1) o += max(n1 - 8, 0);
        if (key > 2) o += max(n2 - 8, 0);
        if (key > 3) o += max(n3 - 8, 0);
        if (key > 4) o += max(n4 - 8, 0);
        if (key > 5) o += max(n5 - 8, 0);
        if (key > 6) o += max(n6 - 8, 0);
        // hole with matching ordinal: key r has max(8-n_r,0) holes at
        // ranks n_r..7 (position j = rank*8 + r)
        int cum = 0;
        j = -1;
        {
            int holes;
            holes = max(8 - n0, 0); if (j < 0 && o < cum + holes) j = (n0 + (o - cum)) * 8 + 0; cum += holes;
            holes = max(8 - n1, 0); if (j < 0 && o < cum + holes) j = (n1 + (o - cum)) * 8 + 1; cum += holes;
            holes = max(8 - n2, 0); if (j < 0 && o < cum + holes) j = (n2 + (o - cum)) * 8 + 2; cum += holes;
            holes = max(8 - n3, 0); if (j < 0 && o < cum + holes) j = (n3 + (o - cum)) * 8 + 3; cum += holes;
            holes = max(8 - n4, 0); if (j < 0 && o < cum + holes) j = (n4 + (o - cum)) * 8 + 4; cum += holes;
            holes = max(8 - n5, 0); if (j < 0 && o < cum + holes) j = (n5 + (o - cum)) * 8 + 5; cum += holes;
            holes = max(8 - n6, 0); if (j < 0 && o < cum + holes) j = (n6 + (o - cum)) * 8 + 6; cum += holes;
            holes = max(8 - n7, 0); if (j < 0 && o < cum + holes) j = (n7 + (o - cum)) * 8 + 7;
        }
    }

    const int dst = ((j >> 2) * NCLASS_ + c) * 4 + (j & 3);
    cmT[dst] = idx;
    wTh[dst] = __float2half2_rn(wv);
}

// float bits <-> packed half2, no address-of-local
static __device__ __forceinline__ __half2 f2h2(const float u) {
    union U { float f; __half2 h; } uu;
    uu.f = u;
    return uu.h;
}
static __device__ __forceinline__ float h2f(const __half2 h) {
    union U { __half2 h; float f; } uu;
    uu.h = h;
    return uu.f;
}

// one support: slot float4 d (8 rows fp16), broadcast half2 weight wj
#define GSUPP(d, wj)                               \
    a0 = __hfma2(f2h2((d).x), (wj), a0);           \
    a1 = __hfma2(f2h2((d).y), (wj), a1);           \
    a2 = __hfma2(f2h2((d).z), (wj), a2);           \
    a3 = __hfma2(f2h2((d).w), (wj), a3);

#define FLUSH_ACC() {                              \
    float2 t_;                                     \
    t_ = __half22float2(a0); f0x += t_.x; f0y += t_.y; \
    t_ = __half22float2(a1); f1x += t_.x; f1y += t_.y; \
    t_ = __half22float2(a2); f2x += t_.x; f2y += t_.y; \
    t_ = __half22float2(a3); f3x += t_.x; f3y += t_.y; \
    a0 = z_; a1 = z_; a2 = z_; a3 = z_; }

template <bool USET>
__global__ __launch_bounds__(THREADS_)
void supp_gather_kernel(const float* __restrict__ x,
                        const float* __restrict__ wSupp,
                        const int*   __restrict__ cmap,
                        const float4* __restrict__ wTh4,
                        const int4*   __restrict__ cmT,
                        float*       __restrict__ out)
{
    // slot idx = 16 B = 8 rows as half2 pairs (rows 2k,2k+1)  -> 64 KB
    __shared__ __align__(16) __half2 tile[NCHUNK_ * 4];

    const int t  = threadIdx.x;
    const int rb = blockIdx.x * BT;   // first batch row of this tile

    // ---- stage: 8 rows of x -> fp16, transposed into LDS ----
    #pragma unroll
    for (int p = 0; p < NCHUNK_ / THREADS_; ++p) {
        const size_t col = (size_t)t + THREADS_ * p;
        float v0 = x[(size_t)(rb + 0) * NCHUNK_ + col];
        float v1 = x[(size_t)(rb + 1) * NCHUNK_ + col];
        float v2 = x[(size_t)(rb + 2) * NCHUNK_ + col];
        float v3 = x[(size_t)(rb + 3) * NCHUNK_ + col];
        float v4 = x[(size_t)(rb + 4) * NCHUNK_ + col];
        float v5 = x[(size_t)(rb + 5) * NCHUNK_ + col];
        float v6 = x[(size_t)(rb + 6) * NCHUNK_ + col];
        float v7 = x[(size_t)(rb + 7) * NCHUNK_ + col];
        float4 pk;
        pk.x = h2f(__floats2half2_rn(v0, v1));
        pk.y = h2f(__floats2half2_rn(v2, v3));
        pk.z = h2f(__floats2half2_rn(v4, v5));
        pk.w = h2f(__floats2half2_rn(v6, v7));
        *reinterpret_cast<float4*>(&tile[col * 4]) = pk;
    }
    __syncthreads();

    // ---- gather: one class per thread, one-deep cm/w pipeline ----
    if (t < NCLASS_) {
        const int c = t;
        const float4* tile4 = reinterpret_cast<const float4*>(tile);

        const __half2 z_ = __floats2half2_rn(0.f, 0.f);
        __half2 a0 = z_, a1 = z_, a2 = z_, a3 = z_;
        float f0x = 0.f, f0y = 0.f, f1x = 0.f, f1y = 0.f;
        float f2x = 0.f, f2y = 0.f, f3x = 0.f, f3y = 0.f;

        // prime the pipeline with sg=0
        int4   ci;
        float4 wh;
        if constexpr (USET) {
            ci = cmT [c];
            wh = wTh4[c];
        } else {
            ci = reinterpret_cast<const int4*>(cmap + c * NSUPP_)[0];
            wh = reinterpret_cast<const float4*>(wSupp + c * NSUPP_)[0];
        }

        #pragma unroll
        for (int sg = 0; sg < SG_; ++sg) {
            const int4   c4 = ci;
            const float4 w4 = wh;

            // prefetch next group's cm/w (L2) past this group's math
            const int sgn = (sg + 1 < SG_) ? sg + 1 : SG_ - 1;
            if constexpr (USET) {
                ci = cmT [sgn * NCLASS_ + c];
                wh = wTh4[sgn * NCLASS_ + c];
            } else {
                ci = reinterpret_cast<const int4*>(cmap + c * NSUPP_)[sgn];
                wh = reinterpret_cast<const float4*>(wSupp + c * NSUPP_)[sgn];
            }

            // 4 independent ds_read_b128, then 16 v_pk_fma_f16
            const float4 d0 = tile4[c4.x];
            const float4 d1 = tile4[c4.y];
            const float4 d2 = tile4[c4.z];
            const float4 d3 = tile4[c4.w];

            const __half2 w0 = USET ? f2h2(w4.x) : __float2half2_rn(w4.x);
            const __half2 w1 = USET ? f2h2(w4.y) : __float2half2_rn(w4.y);
            const __half2 w2 = USET ? f2h2(w4.z) : __float2half2_rn(w4.z);
            const __half2 w3 = USET ? f2h2(w4.w) : __float2half2_rn(w4.w);

            GSUPP(d0, w0)
            GSUPP(d1, w1)
            GSUPP(d2, w2)
            GSUPP(d3, w3)

            // flush fp16 partials to f32 every 4 sg (16 supports):
            // bounds fp16 accumulation error to ~1% of feat
            if ((sg & 3) == 3) { FLUSH_ACC() }
        }

        out[(size_t)(rb + 0) * NCLASS_ + c] = __expf(f0x);
        out[(size_t)(rb + 1) * NCLASS_ + c] = __expf(f0y);
        out[(size_t)(rb + 2) * NCLASS_ + c] = __expf(f1x);
        out[(size_t)(rb + 3) * NCLASS_ + c] = __expf(f1y);
        out[(size_t)(rb + 4) * NCLASS_ + c] = __expf(f2x);
        out[(size_t)(rb + 5) * NCLASS_ + c] = __expf(f2y);
        out[(size_t)(rb + 6) * NCLASS_ + c] = __expf(f3x);
        out[(size_t)(rb + 7) * NCLASS_ + c] = __expf(f3y);
    }
}

extern "C" void kernel_launch(void* const* d_in, const int* in_sizes, int n_in,
                              void* d_out, int out_size, void* d_ws, size_t ws_size,
                              hipStream_t stream) {
    const float* x  = (const float*)d_in[0];   // (B, NCHUNK) fp32
    const float* w  = (const float*)d_in[1];   // (NCLASS, NSUPP) fp32
    const int*   cm = (const int*)d_in[2];     // (NCLASS, NSUPP) int32
    float*       o  = (float*)d_out;           // (B, NCLASS) fp32

    int*     cmT = (int*)d_ws;
    __half2* wTh = (__half2*)((char*)d_ws + CMT_BYTES);

    const dim3 grid(B_ / BT);                  // 512 blocks, 2 per CU
    if (ws_size >= WS_NEEDED) {
        build_cw_kernel<<<dim3((NCLASS_ + 3) / 4), dim3(256), 0, stream>>>(
            cm, w, cmT, wTh);
        supp_gather_kernel<true><<<grid, dim3(THREADS_), 0, stream>>>(
            x, w, cm, (const float4*)wTh, (const int4*)cmT, o);
    } else {
        supp_gather_kernel<false><<<grid, dim3(THREADS_), 0, stream>>>(
            x, w, cm, (const float4*)wTh, (const int4*)cmT, o);
    }
}